// Round 5
// baseline (7922.584 us; speedup 1.0000x reference)
//
#include <hip/hip_runtime.h>

typedef unsigned int uint;
typedef unsigned short ushort;
typedef unsigned long long u64;

// MFMA fragment types (16x16x32 bf16 -> 8 bf16 in, 4 fp32 acc)
typedef short s8v __attribute__((ext_vector_type(8)));
typedef float f4v __attribute__((ext_vector_type(4)));

#define S_LEN 512
#define BATCH 64
#define DH    1024
#define DIN   1024

union B8 { s8v v; uint u[4]; u64 ull[2]; ushort s[8]; };

__device__ inline ushort f2bf(float f){
  uint u = __builtin_bit_cast(uint, f);
  u += 0x7fffu + ((u >> 16) & 1u);
  return (ushort)(u >> 16);
}
__device__ inline float bf2f(ushort s){
  uint u = ((uint)s) << 16;
  return __builtin_bit_cast(float, u);
}

__device__ inline f4v mfma16(s8v a, s8v b, f4v c){
  return __builtin_amdgcn_mfma_f32_16x16x32_bf16(a, b, c, 0, 0, 0);
}

__device__ inline s8v ld_b8(const ushort* p){
  return *reinterpret_cast<const s8v*>(p);
}

__device__ inline u64 ald(const uint* p){
  return __hip_atomic_load((const u64*)p, __ATOMIC_RELAXED, __HIP_MEMORY_SCOPE_AGENT);
}
__device__ inline void ast(uint* p, uint v){
  __hip_atomic_store(p, v, __ATOMIC_RELAXED, __HIP_MEMORY_SCOPE_AGENT);
}

__device__ inline s8v cvt8(float4 a, float4 b){
  B8 r;
  r.s[0]=f2bf(a.x); r.s[1]=f2bf(a.y); r.s[2]=f2bf(a.z); r.s[3]=f2bf(a.w);
  r.s[4]=f2bf(b.x); r.s[5]=f2bf(b.y); r.s[6]=f2bf(b.z); r.s[7]=f2bf(b.w);
  return r.v;
}

// pack 4 tagged u64 (8 words) -> 8-bf16 fragment
__device__ inline s8v extract8(const u64 w[4]){
  B8 o;
  #pragma unroll
  for (int i = 0; i < 4; ++i)
    o.u[i] = (uint)(w[i] & 0xFFFFull) | (((uint)(w[i] >> 32)) << 16);
  return o.v;
}

// MONOTONE tag check: both 16-bit tags in the u64 are >= expected.
// Equal-to-expected in correct runs (overwrite is gated on consumption);
// stale-high state (replays/anomalies) degrades to garbage, never a hang.
__device__ inline bool tags_ok2(u64 w, uint tag){
  return ((((uint)(w >> 16)) & 0xFFFFu) >= tag) & (((uint)(w >> 48)) >= tag);
}

// Seqlock-style poll: every 32-bit word carries (tag<<16)|bf16. The poll
// load IS the data load (single LLC RTT). Bounded spins guarantee
// termination under any state.
template<int NF>
__device__ inline void poll_frags(const uint* __restrict__ base, uint tag, u64 (&aw)[NF][4]){
  // stage 1: cheap 8B probe per fragment
  u64 pr[NF];
  #pragma unroll
  for (int i = 0; i < NF; ++i) pr[i] = ald(base + i*32);
  int guard = 0;
  while (true){
    uint np = 0;
    #pragma unroll
    for (int i = 0; i < NF; ++i) if (!tags_ok2(pr[i], tag)) np |= (1u << i);
    if (__all(np == 0)) break;
    if (++guard > (1 << 16)) break;          // hang-proof escape
    __builtin_amdgcn_s_sleep(4);
    #pragma unroll
    for (int i = 0; i < NF; ++i) if ((np >> i) & 1u) pr[i] = ald(base + i*32);
  }
  // stage 2: full load
  #pragma unroll
  for (int i = 0; i < NF; ++i){
    aw[i][0] = pr[i];
    #pragma unroll
    for (int j = 1; j < 4; ++j) aw[i][j] = ald(base + i*32 + j*2);
  }
  // stage 3: verify + patch stragglers
  uint pend = (uint)((1u << NF) - 1u);
  guard = 0;
  while (true){
    uint np = 0;
    #pragma unroll
    for (int i = 0; i < NF; ++i)
      if ((pend >> i) & 1u){
        bool ok = tags_ok2(aw[i][0], tag) & tags_ok2(aw[i][1], tag)
                & tags_ok2(aw[i][2], tag) & tags_ok2(aw[i][3], tag);
        if (!ok) np |= (1u << i);
      }
    pend = np;
    if (__all(pend == 0)) break;
    if (++guard > (1 << 16)) break;          // hang-proof escape
    #pragma unroll
    for (int i = 0; i < NF; ++i)
      if ((pend >> i) & 1u){
        #pragma unroll
        for (int j = 0; j < 4; ++j) aw[i][j] = ald(base + i*32 + j*2);
      }
  }
}

// ---------------- fp32 -> bf16 conversion (weights) ----------------
__global__ void cvt_kernel(const float* __restrict__ src, ushort* __restrict__ dst, int n){
  int i = (blockIdx.x * blockDim.x + threadIdx.x) * 4;
  if (i + 3 < n){
    float4 v = *reinterpret_cast<const float4*>(src + i);
    u64 p = (u64)f2bf(v.x)
          | ((u64)f2bf(v.y) << 16)
          | ((u64)f2bf(v.z) << 32)
          | ((u64)f2bf(v.w) << 48);
    *reinterpret_cast<u64*>(dst + i) = p;
  }
}

// ---------------- h0 -> tagged word buffer (tag 1) ----------------
__global__ void h0pack_kernel(const float* __restrict__ h0, uint* __restrict__ htag){
  int i = blockIdx.x * blockDim.x + threadIdx.x;
  htag[i] = (1u << 16) | (uint)f2bf(h0[i]);
}

// ---------------- input projections: xz/xr/xn = X @ W^T + b (bf16 out) ----------------
__global__ void __launch_bounds__(256, 1)
proj3_kernel(const float* __restrict__ X,
             const ushort* __restrict__ W0, const ushort* __restrict__ W1, const ushort* __restrict__ W2,
             const float* __restrict__ bias0, const float* __restrict__ bias1, const float* __restrict__ bias2,
             ushort* __restrict__ C0, ushort* __restrict__ C1, ushort* __restrict__ C2)
{
  const int lane = threadIdx.x & 63;
  const int wave = threadIdx.x >> 6;
  const int l15  = lane & 15;
  const int krow = (lane >> 4) << 3;
  const int n0 = blockIdx.x * 64;
  const int m0 = blockIdx.y * 128 + wave * 32;

  const ushort* Ws[3] = {W0, W1, W2};
  const float*  Bs[3] = {bias0, bias1, bias2};
  ushort*       Cs[3] = {C0, C1, C2};

  f4v acc[2][3][4];
  #pragma unroll
  for (int ms = 0; ms < 2; ++ms)
    #pragma unroll
    for (int g = 0; g < 3; ++g)
      #pragma unroll
      for (int nn = 0; nn < 4; ++nn)
        acc[ms][g][nn] = (f4v){0.f,0.f,0.f,0.f};

  const float* a0 = X + (m0 + l15) * DIN + krow;
  const float* a1 = a0 + 16 * DIN;

  for (int k = 0; k < DIN; k += 32){
    s8v af[2];
    {
      const float4* p0 = reinterpret_cast<const float4*>(a0 + k);
      const float4* p1 = reinterpret_cast<const float4*>(a1 + k);
      af[0] = cvt8(p0[0], p0[1]);
      af[1] = cvt8(p1[0], p1[1]);
    }
    #pragma unroll
    for (int g = 0; g < 3; ++g){
      const ushort* W = Ws[g];
      #pragma unroll
      for (int nn = 0; nn < 4; ++nn){
        s8v bfr = ld_b8(W + (n0 + nn*16 + l15) * DIN + k + krow);
        acc[0][g][nn] = mfma16(af[0], bfr, acc[0][g][nn]);
        acc[1][g][nn] = mfma16(af[1], bfr, acc[1][g][nn]);
      }
    }
  }

  #pragma unroll
  for (int g = 0; g < 3; ++g){
    ushort* C = Cs[g];
    #pragma unroll
    for (int nn = 0; nn < 4; ++nn){
      const int n = n0 + nn*16 + l15;
      const float bv = Bs[g][n];
      #pragma unroll
      for (int ms = 0; ms < 2; ++ms){
        #pragma unroll
        for (int r = 0; r < 4; ++r){
          int m = m0 + ms*16 + ((lane>>4)<<2) + r;
          C[m * DH + n] = f2bf(acc[ms][g][nn][r] + bv);
        }
      }
    }
  }
}

// ---------------- output projection: C = hs @ Why^T + b (fp32 out) ----------------
__global__ void __launch_bounds__(256, 1)
gemm1_kernel(const ushort* __restrict__ A, const ushort* __restrict__ W,
             const float* __restrict__ bias, float* __restrict__ C)
{
  const int lane = threadIdx.x & 63;
  const int wave = threadIdx.x >> 6;
  const int l15  = lane & 15;
  const int krow = (lane >> 4) << 3;
  const int n0 = blockIdx.x * 128;
  const int m0 = blockIdx.y * 128 + wave * 32;

  f4v acc[2][8];
  #pragma unroll
  for (int ms = 0; ms < 2; ++ms)
    #pragma unroll
    for (int nn = 0; nn < 8; ++nn)
      acc[ms][nn] = (f4v){0.f,0.f,0.f,0.f};

  const ushort* a0 = A + (m0 + l15) * DH + krow;
  const ushort* a1 = a0 + 16 * DH;

  for (int k = 0; k < DH; k += 32){
    s8v af0 = ld_b8(a0 + k);
    s8v af1 = ld_b8(a1 + k);
    #pragma unroll
    for (int nn = 0; nn < 8; ++nn){
      s8v b = ld_b8(W + (n0 + nn*16 + l15) * DH + k + krow);
      acc[0][nn] = mfma16(af0, b, acc[0][nn]);
      acc[1][nn] = mfma16(af1, b, acc[1][nn]);
    }
  }

  #pragma unroll
  for (int nn = 0; nn < 8; ++nn){
    const int n = n0 + nn*16 + l15;
    const float bv = bias[n];
    #pragma unroll
    for (int ms = 0; ms < 2; ++ms){
      #pragma unroll
      for (int r = 0; r < 4; ++r){
        int m = m0 + ms*16 + ((lane>>4)<<2) + r;
        C[m * DH + n] = acc[ms][nn][r] + bv;
      }
    }
  }
}

// ---------------- the GRU scan ----------------
// 256 wgs x 256 thr (proven shape): wg (g = wid>>6, jt = wid&63) owns a
// 16b x 16j tile; 4 waves split K into quarters of 256. Recurrent weights
// register-resident (24 s8v = 96 VGPRs). Exchange via single-slot
// tagged-word buffers: htag carries h(t) with tag t+2 (h0 = tag 1),
// rhtag carries rh(t) with tag t+1. Single-slot reuse is safe because the
// full-K dependence makes the grid lockstep: any producer's write of tag
// T+1 is transitively gated (through its own wg-barrier + polls) on every
// consumer's completed read of tag T.
__global__ void __launch_bounds__(256, 1)
scan_kernel(const ushort* __restrict__ xz, const ushort* __restrict__ xr,
            const ushort* __restrict__ xn,
            const ushort* __restrict__ Whz, const ushort* __restrict__ Whr,
            const ushort* __restrict__ Whn,
            const float* __restrict__ h0,
            uint* __restrict__ htag, uint* __restrict__ rhtag,
            ushort* __restrict__ hs, float* __restrict__ hlast)
{
  const int tid  = threadIdx.x;
  const int wave = tid >> 6;          // 0..3 = K-quarter
  const int lane = tid & 63;
  const int l15  = lane & 15;
  const int hi2  = lane >> 4;         // 0..3
  const int krow = hi2 << 3;          // 0,8,16,24
  const int wid  = blockIdx.x;
  const int b0   = (wid >> 6) << 4;   // batch group base
  const int j0   = (wid & 63) << 4;   // hidden tile base
  const int kbase = wave << 8;        // 0,256,512,768

  // separate A/B reduce buffers; each protected by the alternating barriers
  __shared__ float redA[8][256];      // [wave] z, [4+wave] r partials
  __shared__ float redB[4][256];      // n partials

  // register-stationary recurrent weights: 24 x s8v = 96 VGPRs
  s8v wz[8], wr[8], wn[8];
  {
    const int wbase = (j0 + l15) * DH + kbase + krow;
    #pragma unroll
    for (int kk = 0; kk < 8; ++kk){
      wz[kk] = ld_b8(Whz + wbase + kk*32);
      wr[kk] = ld_b8(Whr + wbase + kk*32);
      wn[kk] = ld_b8(Whn + wbase + kk*32);
    }
  }

  // per-thread owned output element (bl, jl)
  const int bl = tid >> 4;
  const int jl = tid & 15;
  const int brow = b0 + bl;
  const int jcol = j0 + jl;
  float h = h0[brow * DH + jcol];

  const uint* hpoll  = htag  + (b0 + l15)*DH + kbase + krow;
  const uint* rhpoll = rhtag + (b0 + l15)*DH + kbase + krow;
  uint* rhdst = rhtag + brow*DH + jcol;
  uint* hdst  = htag  + brow*DH + jcol;

  const int lbase = hi2*64 + l15;     // LDS partial base: (hi2*4+r)*16+l15

  u64 aw[8][4];                       // 64 VGPRs, reused by both phases
  float zreg = 0.f;

  #pragma unroll 1
  for (int t = 0; t < S_LEN; ++t){
    const int xidx = (t*BATCH + brow)*DH + jcol;

    // ---- phase A: z, r ----
    float xzv = bf2f(xz[xidx]);
    float xrv = bf2f(xr[xidx]);

    poll_frags<8>(hpoll, (uint)(t + 1), aw);

    f4v az0={0.f,0.f,0.f,0.f}, az1={0.f,0.f,0.f,0.f};
    f4v ar0={0.f,0.f,0.f,0.f}, ar1={0.f,0.f,0.f,0.f};
    #pragma unroll
    for (int i = 0; i < 8; i += 2){
      s8v a0 = extract8(aw[i]);
      s8v a1 = extract8(aw[i+1]);
      az0 = mfma16(a0, wz[i],   az0);
      ar0 = mfma16(a0, wr[i],   ar0);
      az1 = mfma16(a1, wz[i+1], az1);
      ar1 = mfma16(a1, wr[i+1], ar1);
    }

    #pragma unroll
    for (int r = 0; r < 4; ++r){
      redA[wave][lbase + r*16]   = az0[r] + az1[r];
      redA[4+wave][lbase + r*16] = ar0[r] + ar1[r];
    }
    __syncthreads();

    float sz = redA[0][tid] + redA[1][tid] + redA[2][tid] + redA[3][tid];
    float sr = redA[4][tid] + redA[5][tid] + redA[6][tid] + redA[7][tid];
    float z = 1.f / (1.f + __expf(-(xzv + sz)));
    float r = 1.f / (1.f + __expf(-(xrv + sr)));
    zreg = z;
    float rh = r * h;
    ast(rhdst, (((uint)(t + 1)) << 16) | (uint)f2bf(rh));

    // ---- phase B: n, h update ----
    float xnv = bf2f(xn[xidx]);

    poll_frags<8>(rhpoll, (uint)(t + 1), aw);

    f4v an0={0.f,0.f,0.f,0.f}, an1={0.f,0.f,0.f,0.f};
    #pragma unroll
    for (int i = 0; i < 8; i += 2){
      s8v a0 = extract8(aw[i]);
      s8v a1 = extract8(aw[i+1]);
      an0 = mfma16(a0, wn[i],   an0);
      an1 = mfma16(a1, wn[i+1], an1);
    }

    #pragma unroll
    for (int r4 = 0; r4 < 4; ++r4)
      redB[wave][lbase + r4*16] = an0[r4] + an1[r4];
    __syncthreads();

    float sn = redB[0][tid] + redB[1][tid] + redB[2][tid] + redB[3][tid];
    float pre = xnv + sn;
    float e = __expf(2.f * pre);
    float nv = 1.f - 2.f / (e + 1.f);
    float hnew = h + zreg * (nv - h);
    h = hnew;

    ushort hbf = f2bf(hnew);
    ast(hdst, (((uint)(t + 2)) << 16) | (uint)hbf);   // publish first
    hs[xidx] = hbf;
    if (t == S_LEN - 1) hlast[brow*DH + jcol] = hnew;
  }
}

extern "C" void kernel_launch(void* const* d_in, const int* in_sizes, int n_in,
                              void* d_out, int out_size, void* d_ws, size_t ws_size,
                              hipStream_t stream) {
  const float* x_seq = (const float*)d_in[0];
  const float* h0    = (const float*)d_in[1];
  const float* Wxz_w = (const float*)d_in[2];
  const float* Wxz_b = (const float*)d_in[3];
  const float* Whz_w = (const float*)d_in[4];
  const float* Wxr_w = (const float*)d_in[5];
  const float* Wxr_b = (const float*)d_in[6];
  const float* Whr_w = (const float*)d_in[7];
  const float* Wxn_w = (const float*)d_in[8];
  const float* Wxn_b = (const float*)d_in[9];
  const float* Whn_w = (const float*)d_in[10];
  const float* Why_w = (const float*)d_in[11];
  const float* Why_b = (const float*)d_in[12];

  const size_t MiB = 1u << 20;
  unsigned char* ws = (unsigned char*)d_ws;

  ushort* Whz16 = (ushort*)(ws + 0*MiB);
  ushort* Whr16 = (ushort*)(ws + 2*MiB);
  ushort* Whn16 = (ushort*)(ws + 4*MiB);
  ushort* Wxz16 = (ushort*)(ws + 6*MiB);
  ushort* Wxr16 = (ushort*)(ws + 8*MiB);
  ushort* Wxn16 = (ushort*)(ws + 10*MiB);
  ushort* Why16 = (ushort*)(ws + 12*MiB);
  ushort* xn_buf = (ushort*)(ws + 16*MiB);          // 64 MiB
  ushort* hs     = (ushort*)(ws + 80*MiB);          // 64 MiB (plain, for gemm1)
  uint*   htag   = (uint*)  (ws + 144*MiB);         // 256 KiB single slot
  uint*   rhtag  = (uint*)  (ws + 144*MiB + 256*1024); // 256 KiB single slot
  // total ws footprint: 144.5 MiB

  // xz/xr live in d_out as bf16 scratch (overwritten by gemm1 later; h_last tail disjoint)
  ushort* xz_buf = (ushort*)d_out;                  // 64 MiB
  ushort* xr_buf = xz_buf + (size_t)S_LEN*BATCH*DH; // 64 MiB
  float*  out_f  = (float*)d_out;
  float*  hlast  = out_f + (size_t)S_LEN*BATCH*DH;

  const int NW = DH * DIN;

  cvt_kernel<<<1024, 256, 0, stream>>>(Whz_w, Whz16, NW);
  cvt_kernel<<<1024, 256, 0, stream>>>(Whr_w, Whr16, NW);
  cvt_kernel<<<1024, 256, 0, stream>>>(Whn_w, Whn16, NW);
  cvt_kernel<<<1024, 256, 0, stream>>>(Wxz_w, Wxz16, NW);
  cvt_kernel<<<1024, 256, 0, stream>>>(Wxr_w, Wxr16, NW);
  cvt_kernel<<<1024, 256, 0, stream>>>(Wxn_w, Wxn16, NW);
  cvt_kernel<<<1024, 256, 0, stream>>>(Why_w, Why16, NW);

  proj3_kernel<<<dim3(16, 256), 256, 0, stream>>>(
      x_seq, Wxz16, Wxr16, Wxn16, Wxz_b, Wxr_b, Wxn_b, xz_buf, xr_buf, xn_buf);

  // rhtag: tag 0 = invalid (re-poison each launch); htag fully rewritten below
  hipMemsetAsync((void*)rhtag, 0, (size_t)BATCH*DH*sizeof(uint), stream);
  h0pack_kernel<<<256, 256, 0, stream>>>(h0, htag);

  scan_kernel<<<256, 256, 0, stream>>>(
      xz_buf, xr_buf, xn_buf, Whz16, Whr16, Whn16, h0,
      htag, rhtag, hs, hlast);

  gemm1_kernel<<<dim3(8, 256), 256, 0, stream>>>(hs, Why16, Why_b, out_f);
}

// Round 6
// 5563.302 us; speedup vs baseline: 1.4241x; 1.4241x over previous
//
#include <hip/hip_runtime.h>

typedef unsigned int uint;
typedef unsigned short ushort;
typedef unsigned long long u64;

// MFMA fragment types (16x16x32 bf16 -> 8 bf16 in, 4 fp32 acc)
typedef short s8v __attribute__((ext_vector_type(8)));
typedef float f4v __attribute__((ext_vector_type(4)));

#define S_LEN 512
#define BATCH 64
#define DH    1024
#define DIN   1024

union B8 { s8v v; uint u[4]; u64 ull[2]; ushort s[8]; };

__device__ inline ushort f2bf(float f){
  uint u = __builtin_bit_cast(uint, f);
  u += 0x7fffu + ((u >> 16) & 1u);
  return (ushort)(u >> 16);
}
__device__ inline float bf2f(ushort s){
  uint u = ((uint)s) << 16;
  return __builtin_bit_cast(float, u);
}

__device__ inline f4v mfma16(s8v a, s8v b, f4v c){
  return __builtin_amdgcn_mfma_f32_16x16x32_bf16(a, b, c, 0, 0, 0);
}

__device__ inline s8v ld_b8(const ushort* p){
  return *reinterpret_cast<const s8v*>(p);
}

// LLC-coherent 16B fragment load as 2x8B relaxed agent atomics (freshness;
// per-element atomicity not required — validity comes from the flag protocol)
__device__ inline s8v ld_b8_llc(const ushort* p){
  B8 b;
  const u64* q = (const u64*)p;
  b.ull[0] = __hip_atomic_load(q,   __ATOMIC_RELAXED, __HIP_MEMORY_SCOPE_AGENT);
  b.ull[1] = __hip_atomic_load(q+1, __ATOMIC_RELAXED, __HIP_MEMORY_SCOPE_AGENT);
  return b.v;
}

__device__ inline uint ald32(const uint* p){
  return __hip_atomic_load(p, __ATOMIC_RELAXED, __HIP_MEMORY_SCOPE_AGENT);
}
__device__ inline void ast32(uint* p, uint v){
  __hip_atomic_store(p, v, __ATOMIC_RELAXED, __HIP_MEMORY_SCOPE_AGENT);
}

__device__ inline s8v cvt8(float4 a, float4 b){
  B8 r;
  r.s[0]=f2bf(a.x); r.s[1]=f2bf(a.y); r.s[2]=f2bf(a.z); r.s[3]=f2bf(a.w);
  r.s[4]=f2bf(b.x); r.s[5]=f2bf(b.y); r.s[6]=f2bf(b.z); r.s[7]=f2bf(b.w);
  return r.v;
}

// ---------------- fp32 -> bf16 conversion (weights) ----------------
__global__ void cvt_kernel(const float* __restrict__ src, ushort* __restrict__ dst, int n){
  int i = (blockIdx.x * blockDim.x + threadIdx.x) * 4;
  if (i + 3 < n){
    float4 v = *reinterpret_cast<const float4*>(src + i);
    u64 p = (u64)f2bf(v.x)
          | ((u64)f2bf(v.y) << 16)
          | ((u64)f2bf(v.z) << 32)
          | ((u64)f2bf(v.w) << 48);
    *reinterpret_cast<u64*>(dst + i) = p;
  }
}

// ---------------- input projections: xz/xr/xn = X @ W^T + b (bf16 out) ----------------
__global__ void __launch_bounds__(256, 1)
proj3_kernel(const float* __restrict__ X,
             const ushort* __restrict__ W0, const ushort* __restrict__ W1, const ushort* __restrict__ W2,
             const float* __restrict__ bias0, const float* __restrict__ bias1, const float* __restrict__ bias2,
             ushort* __restrict__ C0, ushort* __restrict__ C1, ushort* __restrict__ C2)
{
  const int lane = threadIdx.x & 63;
  const int wave = threadIdx.x >> 6;
  const int l15  = lane & 15;
  const int krow = (lane >> 4) << 3;
  const int n0 = blockIdx.x * 64;
  const int m0 = blockIdx.y * 128 + wave * 32;

  const ushort* Ws[3] = {W0, W1, W2};
  const float*  Bs[3] = {bias0, bias1, bias2};
  ushort*       Cs[3] = {C0, C1, C2};

  f4v acc[2][3][4];
  #pragma unroll
  for (int ms = 0; ms < 2; ++ms)
    #pragma unroll
    for (int g = 0; g < 3; ++g)
      #pragma unroll
      for (int nn = 0; nn < 4; ++nn)
        acc[ms][g][nn] = (f4v){0.f,0.f,0.f,0.f};

  const float* a0 = X + (m0 + l15) * DIN + krow;
  const float* a1 = a0 + 16 * DIN;

  for (int k = 0; k < DIN; k += 32){
    s8v af[2];
    {
      const float4* p0 = reinterpret_cast<const float4*>(a0 + k);
      const float4* p1 = reinterpret_cast<const float4*>(a1 + k);
      af[0] = cvt8(p0[0], p0[1]);
      af[1] = cvt8(p1[0], p1[1]);
    }
    #pragma unroll
    for (int g = 0; g < 3; ++g){
      const ushort* W = Ws[g];
      #pragma unroll
      for (int nn = 0; nn < 4; ++nn){
        s8v bfr = ld_b8(W + (n0 + nn*16 + l15) * DIN + k + krow);
        acc[0][g][nn] = mfma16(af[0], bfr, acc[0][g][nn]);
        acc[1][g][nn] = mfma16(af[1], bfr, acc[1][g][nn]);
      }
    }
  }

  #pragma unroll
  for (int g = 0; g < 3; ++g){
    ushort* C = Cs[g];
    #pragma unroll
    for (int nn = 0; nn < 4; ++nn){
      const int n = n0 + nn*16 + l15;
      const float bv = Bs[g][n];
      #pragma unroll
      for (int ms = 0; ms < 2; ++ms){
        #pragma unroll
        for (int r = 0; r < 4; ++r){
          int m = m0 + ms*16 + ((lane>>4)<<2) + r;
          C[m * DH + n] = f2bf(acc[ms][g][nn][r] + bv);
        }
      }
    }
  }
}

// ---------------- output projection: C = hs @ Why^T + b (fp32 out) ----------------
__global__ void __launch_bounds__(256, 1)
gemm1_kernel(const ushort* __restrict__ A, const ushort* __restrict__ W,
             const float* __restrict__ bias, float* __restrict__ C)
{
  const int lane = threadIdx.x & 63;
  const int wave = threadIdx.x >> 6;
  const int l15  = lane & 15;
  const int krow = (lane >> 4) << 3;
  const int n0 = blockIdx.x * 128;
  const int m0 = blockIdx.y * 128 + wave * 32;

  f4v acc[2][8];
  #pragma unroll
  for (int ms = 0; ms < 2; ++ms)
    #pragma unroll
    for (int nn = 0; nn < 8; ++nn)
      acc[ms][nn] = (f4v){0.f,0.f,0.f,0.f};

  const ushort* a0 = A + (m0 + l15) * DH + krow;
  const ushort* a1 = a0 + 16 * DH;

  for (int k = 0; k < DH; k += 32){
    s8v af0 = ld_b8(a0 + k);
    s8v af1 = ld_b8(a1 + k);
    #pragma unroll
    for (int nn = 0; nn < 8; ++nn){
      s8v b = ld_b8(W + (n0 + nn*16 + l15) * DH + k + krow);
      acc[0][nn] = mfma16(af0, b, acc[0][nn]);
      acc[1][nn] = mfma16(af1, b, acc[1][nn]);
    }
  }

  #pragma unroll
  for (int nn = 0; nn < 8; ++nn){
    const int n = n0 + nn*16 + l15;
    const float bv = bias[n];
    #pragma unroll
    for (int ms = 0; ms < 2; ++ms){
      #pragma unroll
      for (int r = 0; r < 4; ++r){
        int m = m0 + ms*16 + ((lane>>4)<<2) + r;
        C[m * DH + n] = acc[ms][nn][r] + bv;
      }
    }
  }
}

// ---------------- the GRU scan ----------------
// 128 wgs x 256 thr. wg = (group g = wid>>5 owning batches [16g,16g+16),
// j-tile jt = wid&31 owning 32 hidden cols). 4 waves K-split (256 each).
// All three recurrent weight matrices register-stationary (48 s8v = 192
// VGPRs; __launch_bounds__(256,1) gives the 512-VGPR budget).
// R0-proven protocol: untagged bf16 double-buffered h/rh through LLC (agent
// atomics), monotone per-wg flags published after a drain barrier, per-wave
// flag subsets (wave w only waits for the 8 producers of its K-slice).
// vs R0: half the sync width (32 vs 64 wgs/group), half the per-phase
// redundant exchange reads (1 MB vs 2 MB per group), packed 4B x-loads.
__global__ void __launch_bounds__(256, 1)
scan_kernel(const ushort* __restrict__ xz, const ushort* __restrict__ xr,
            const ushort* __restrict__ xn,
            const ushort* __restrict__ Whz, const ushort* __restrict__ Whr,
            const ushort* __restrict__ Whn,
            const float* __restrict__ h0,
            ushort* __restrict__ hbuf,     // 2 x 64*1024 bf16
            ushort* __restrict__ rhbuf,    // 2 x 64*1024 bf16
            ushort* __restrict__ hs,       // 512*64*1024 bf16
            float*  __restrict__ hlast,    // 64*1024 f32
            uint* __restrict__ hflags,     // 128 wgs * 4 uints
            uint* __restrict__ rhflags)
{
  const int tid  = threadIdx.x;
  const int wave = tid >> 6;          // 0..3 = K-quarter
  const int lane = tid & 63;
  const int l15  = lane & 15;
  const int hi2  = lane >> 4;         // 0..3
  const int krow = hi2 << 3;          // 0,8,16,24
  const int wid  = blockIdx.x;
  const int g    = wid >> 5;          // batch group 0..3
  const int jt   = wid & 31;          // j-tile 0..31
  const int b0   = g << 4;
  const int j0   = jt << 5;           // 32 cols per wg
  const int kbase = wave << 8;        // 0,256,512,768

  __shared__ float redA[2][4][512];   // [z/r][wave][16 rows x 32 cols]
  __shared__ float redB[4][512];      // n partials

  // register-stationary recurrent weights: 48 x s8v = 192 VGPRs
  s8v wz[2][8], wr[2][8], wn[2][8];
  #pragma unroll
  for (int nn = 0; nn < 2; ++nn){
    const int wbase = (j0 + nn*16 + l15) * DH + kbase + krow;
    #pragma unroll
    for (int kk = 0; kk < 8; ++kk){
      wz[nn][kk] = ld_b8(Whz + wbase + kk*32);
      wr[nn][kk] = ld_b8(Whr + wbase + kk*32);
      wn[nn][kk] = ld_b8(Whn + wbase + kk*32);
    }
  }

  // per-thread owned output pair: row brow, cols jcol, jcol+1
  const int bl   = tid >> 4;          // 0..15
  const int jl2  = (tid & 15) << 1;   // 0,2,...,30
  const int brow = b0 + bl;
  const int jcol = j0 + jl2;
  float2 h2 = *reinterpret_cast<const float2*>(h0 + brow * DH + jcol);
  float hr0 = h2.x, hr1 = h2.y;

  const int arow = b0 + l15;          // MFMA A-operand row for this lane
  // wave w's K-slice [w*256,(w+1)*256) is produced by wgs jt in [w*8,w*8+8)
  const uint* hfp  = hflags  + (g*32 + wave*8 + (l15 & 7)) * 4;
  const uint* rhfp = rhflags + (g*32 + wave*8 + (l15 & 7)) * 4;
  uint* rhdst = (uint*)(rhbuf) ;      // recomputed per t below
  (void)rhdst;

  // init h_{-1} = h0 into hbuf slot 1 (t=0 reads slot (0^1)&1 = 1)
  {
    uint pack = (uint)f2bf(hr0) | ((uint)f2bf(hr1) << 16);
    ast32((uint*)(hbuf + 64*1024 + brow*DH + jcol), pack);
  }
  __syncthreads();   // drains vmcnt before flag publish
  if (tid == 0)
    ast32(&hflags[wid*4], 1u);

  float z0 = 0.f, z1 = 0.f;

  #pragma unroll 1
  for (int t = 0; t < S_LEN; ++t){
    const int xidx = (t * BATCH + brow) * DH + jcol;

    // ---- phase A: z, r ----
    uint xzp = *reinterpret_cast<const uint*>(xz + xidx);
    uint xrp = *reinterpret_cast<const uint*>(xr + xidx);
    float xzv0 = bf2f((ushort)(xzp & 0xFFFFu)), xzv1 = bf2f((ushort)(xzp >> 16));
    float xrv0 = bf2f((ushort)(xrp & 0xFFFFu)), xrv1 = bf2f((ushort)(xrp >> 16));

    {
      const uint tgt = (uint)(t + 1);
      while (true){
        uint v = ald32(hfp);
        if (__all(v >= tgt)) break;
        __builtin_amdgcn_s_sleep(2);
      }
    }
    __asm__ volatile("" ::: "memory");

    f4v az[2] = {(f4v){0.f,0.f,0.f,0.f}, (f4v){0.f,0.f,0.f,0.f}};
    f4v ar[2] = {(f4v){0.f,0.f,0.f,0.f}, (f4v){0.f,0.f,0.f,0.f}};
    {
      const ushort* ap = hbuf + ((t ^ 1) & 1) * (64*1024) + arow * DH + kbase + krow;
      #pragma unroll
      for (int kk = 0; kk < 8; ++kk){
        s8v a = ld_b8_llc(ap + kk*32);
        az[0] = mfma16(a, wz[0][kk], az[0]);
        az[1] = mfma16(a, wz[1][kk], az[1]);
        ar[0] = mfma16(a, wr[0][kk], ar[0]);
        ar[1] = mfma16(a, wr[1][kk], ar[1]);
      }
    }
    #pragma unroll
    for (int nn = 0; nn < 2; ++nn)
      #pragma unroll
      for (int r = 0; r < 4; ++r){
        const int e = (hi2*4 + r)*32 + nn*16 + l15;
        redA[0][wave][e] = az[nn][r];
        redA[1][wave][e] = ar[nn][r];
      }
    __syncthreads();

    const int e0 = bl*32 + jl2;
    float sz0 = redA[0][0][e0]   + redA[0][1][e0]   + redA[0][2][e0]   + redA[0][3][e0];
    float sz1 = redA[0][0][e0+1] + redA[0][1][e0+1] + redA[0][2][e0+1] + redA[0][3][e0+1];
    float sr0 = redA[1][0][e0]   + redA[1][1][e0]   + redA[1][2][e0]   + redA[1][3][e0];
    float sr1 = redA[1][0][e0+1] + redA[1][1][e0+1] + redA[1][2][e0+1] + redA[1][3][e0+1];
    z0 = 1.f / (1.f + __expf(-(xzv0 + sz0)));
    z1 = 1.f / (1.f + __expf(-(xzv1 + sz1)));
    float r0 = 1.f / (1.f + __expf(-(xrv0 + sr0)));
    float r1 = 1.f / (1.f + __expf(-(xrv1 + sr1)));
    float rh0 = r0 * hr0;
    float rh1 = r1 * hr1;
    {
      uint pack = (uint)f2bf(rh0) | ((uint)f2bf(rh1) << 16);
      ast32((uint*)(rhbuf + (t & 1)*(64*1024) + brow*DH + jcol), pack);
    }
    __syncthreads();   // redA reads done + rh stores drained
    if (tid == 0)
      ast32(&rhflags[wid*4], (uint)(t + 1));

    // ---- phase B: n, h update ----
    uint xnp = *reinterpret_cast<const uint*>(xn + xidx);
    float xnv0 = bf2f((ushort)(xnp & 0xFFFFu)), xnv1 = bf2f((ushort)(xnp >> 16));

    {
      const uint tgt = (uint)(t + 1);
      while (true){
        uint v = ald32(rhfp);
        if (__all(v >= tgt)) break;
        __builtin_amdgcn_s_sleep(2);
      }
    }
    __asm__ volatile("" ::: "memory");

    f4v an[2] = {(f4v){0.f,0.f,0.f,0.f}, (f4v){0.f,0.f,0.f,0.f}};
    {
      const ushort* ap = rhbuf + (t & 1)*(64*1024) + arow * DH + kbase + krow;
      #pragma unroll
      for (int kk = 0; kk < 8; ++kk){
        s8v a = ld_b8_llc(ap + kk*32);
        an[0] = mfma16(a, wn[0][kk], an[0]);
        an[1] = mfma16(a, wn[1][kk], an[1]);
      }
    }
    #pragma unroll
    for (int nn = 0; nn < 2; ++nn)
      #pragma unroll
      for (int r = 0; r < 4; ++r){
        const int e = (hi2*4 + r)*32 + nn*16 + l15;
        redB[wave][e] = an[nn][r];
      }
    __syncthreads();

    float sn0 = redB[0][e0]   + redB[1][e0]   + redB[2][e0]   + redB[3][e0];
    float sn1 = redB[0][e0+1] + redB[1][e0+1] + redB[2][e0+1] + redB[3][e0+1];
    float pre0 = xnv0 + sn0;
    float pre1 = xnv1 + sn1;
    float e_0 = __expf(2.f * pre0);
    float e_1 = __expf(2.f * pre1);
    float n0 = 1.f - 2.f / (e_0 + 1.f);
    float n1 = 1.f - 2.f / (e_1 + 1.f);
    float hn0 = hr0 + z0 * (n0 - hr0);
    float hn1 = hr1 + z1 * (n1 - hr1);
    hr0 = hn0; hr1 = hn1;

    {
      uint pack = (uint)f2bf(hn0) | ((uint)f2bf(hn1) << 16);
      ast32((uint*)(hbuf + (t & 1)*(64*1024) + brow*DH + jcol), pack);
      *reinterpret_cast<uint*>(hs + xidx) = pack;   // plain store; next kernel
      if (t == S_LEN - 1){
        float2 hl; hl.x = hn0; hl.y = hn1;
        *reinterpret_cast<float2*>(hlast + brow*DH + jcol) = hl;
      }
    }
    __syncthreads();   // drains vmcnt
    if (tid == 0)
      ast32(&hflags[wid*4], (uint)(t + 2));
  }
}

extern "C" void kernel_launch(void* const* d_in, const int* in_sizes, int n_in,
                              void* d_out, int out_size, void* d_ws, size_t ws_size,
                              hipStream_t stream) {
  const float* x_seq = (const float*)d_in[0];
  const float* h0    = (const float*)d_in[1];
  const float* Wxz_w = (const float*)d_in[2];
  const float* Wxz_b = (const float*)d_in[3];
  const float* Whz_w = (const float*)d_in[4];
  const float* Wxr_w = (const float*)d_in[5];
  const float* Wxr_b = (const float*)d_in[6];
  const float* Whr_w = (const float*)d_in[7];
  const float* Wxn_w = (const float*)d_in[8];
  const float* Wxn_b = (const float*)d_in[9];
  const float* Whn_w = (const float*)d_in[10];
  const float* Why_w = (const float*)d_in[11];
  const float* Why_b = (const float*)d_in[12];

  const size_t MiB = 1u << 20;
  unsigned char* ws = (unsigned char*)d_ws;

  ushort* Whz16 = (ushort*)(ws + 0*MiB);
  ushort* Whr16 = (ushort*)(ws + 2*MiB);
  ushort* Whn16 = (ushort*)(ws + 4*MiB);
  ushort* Wxz16 = (ushort*)(ws + 6*MiB);
  ushort* Wxr16 = (ushort*)(ws + 8*MiB);
  ushort* Wxn16 = (ushort*)(ws + 10*MiB);
  ushort* Why16 = (ushort*)(ws + 12*MiB);
  ushort* xn_buf = (ushort*)(ws + 16*MiB);          // 64 MiB
  ushort* hs     = (ushort*)(ws + 80*MiB);          // 64 MiB
  ushort* hbuf   = (ushort*)(ws + 144*MiB);         // 256 KiB (2 slots)
  ushort* rhbuf  = (ushort*)(ws + 144*MiB + 256*1024);
  uint*   hflags = (uint*)  (ws + 144*MiB + 512*1024);  // 2 KiB
  uint*   rhflags= (uint*)  (ws + 144*MiB + 512*1024 + 2048);

  // xz/xr live in d_out as bf16 scratch (overwritten by gemm1 later; h_last tail disjoint)
  ushort* xz_buf = (ushort*)d_out;                  // 64 MiB
  ushort* xr_buf = xz_buf + (size_t)S_LEN*BATCH*DH; // 64 MiB
  float*  out_f  = (float*)d_out;
  float*  hlast  = out_f + (size_t)S_LEN*BATCH*DH;

  const int NW = DH * DIN; // 1048576 elems per weight matrix

  cvt_kernel<<<1024, 256, 0, stream>>>(Whz_w, Whz16, NW);
  cvt_kernel<<<1024, 256, 0, stream>>>(Whr_w, Whr16, NW);
  cvt_kernel<<<1024, 256, 0, stream>>>(Whn_w, Whn16, NW);
  cvt_kernel<<<1024, 256, 0, stream>>>(Wxz_w, Wxz16, NW);
  cvt_kernel<<<1024, 256, 0, stream>>>(Wxr_w, Wxr16, NW);
  cvt_kernel<<<1024, 256, 0, stream>>>(Wxn_w, Wxn16, NW);
  cvt_kernel<<<1024, 256, 0, stream>>>(Why_w, Why16, NW);

  proj3_kernel<<<dim3(16, 256), 256, 0, stream>>>(
      x_seq, Wxz16, Wxr16, Wxn16, Wxz_b, Wxr_b, Wxn_b, xz_buf, xr_buf, xn_buf);

  // flags: monotone, re-poisoned to 0 each launch (covers hflags + rhflags)
  hipMemsetAsync((void*)hflags, 0, 4096, stream);

  scan_kernel<<<128, 256, 0, stream>>>(
      xz_buf, xr_buf, xn_buf, Whz16, Whr16, Whn16, h0,
      hbuf, rhbuf, hs, hlast, hflags, rhflags);

  gemm1_kernel<<<dim3(8, 256), 256, 0, stream>>>(hs, Why16, Why_b, out_f);
}